// Round 1
// baseline (112.565 us; speedup 1.0000x reference)
//
#include <hip/hip_runtime.h>

// Problem constants (from the reference)
#define BB     256   // batch
#define S      64    // SIZE
#define EE     4096  // E
#define NROWS  17    // 1 + ADDITIONAL

// ---------------------------------------------------------------------------
// Kernel 1: per-batch weight computation.
// One block (64 threads = 1 wave) per batch.
//   - pack the 17 choice rows into uint64 masks via __ballot (lane i = col i)
//   - prob[j] = prod_i (bit ? off[i] : 1-off[i])   (f32, like the reference)
//   - normalize over ALL 17 rows, THEN zero duplicates (reference order)
//   - W1[i] = sum_j prob'[j]*bit_ji ; W0[i] = sum_j prob'[j]*(1-bit_ji)
//   - keys_out[b,r] = wa*keys[c0] + wb*keys[c1]  (each M-row has <=2 nnz)
// ---------------------------------------------------------------------------
__global__ __launch_bounds__(64) void split_weights_kernel(
    const float* __restrict__ keys,     // [BB][S]
    const float* __restrict__ offset,   // [BB][S]
    const int*   __restrict__ bits,     // [BB][NROWS-1][S]
    float* __restrict__ W0,             // [BB][S]
    float* __restrict__ W1,             // [BB][S]
    float* __restrict__ keys_out)       // [BB][S]
{
    const int b    = blockIdx.x;
    const int lane = threadIdx.x;   // 0..63, one full wave

    __shared__ float              s_off[S];
    __shared__ unsigned long long s_mask[NROWS];
    __shared__ float              s_prob[NROWS];
    __shared__ float              s_W0[S], s_W1[S];
    __shared__ float              s_sum;

    const float off = offset[b * S + lane];
    s_off[lane] = off;

    // first row: round-half-even of offset (matches jnp.round)
    const int fb = (int)rintf(off);
    unsigned long long m = __ballot(fb == 1);
    if (lane == 0) s_mask[0] = m;
    // 16 sampled rows
    for (int j = 0; j < NROWS - 1; ++j) {
        const int bit = bits[((size_t)b * (NROWS - 1) + j) * S + lane];
        m = __ballot(bit == 1);
        if (lane == 0) s_mask[1 + j] = m;
    }
    __syncthreads();

    // per-row probability products (threads 0..16)
    if (lane < NROWS) {
        const unsigned long long mk = s_mask[lane];
        float p = 1.0f;
        #pragma unroll
        for (int i = 0; i < S; ++i) {
            const float o = s_off[i];
            p *= ((mk >> i) & 1ull) ? o : (1.0f - o);
        }
        s_prob[lane] = p;
    }
    __syncthreads();

    if (lane == 0) {
        float sum = 0.0f;
        #pragma unroll
        for (int j = 0; j < NROWS; ++j) sum += s_prob[j];
        s_sum = sum;
    }
    __syncthreads();

    // normalize (by sum over all 17, dups included), then zero later duplicates
    if (lane < NROWS) {
        const unsigned long long mk = s_mask[lane];
        bool dup = false;
        for (int k = 0; k < lane; ++k) dup |= (s_mask[k] == mk);
        s_prob[lane] = dup ? 0.0f : (s_prob[lane] / s_sum);
    }
    __syncthreads();

    // per-column split weights
    {
        float w0 = 0.0f, w1 = 0.0f;
        #pragma unroll
        for (int j = 0; j < NROWS; ++j) {
            const float p = s_prob[j];
            if ((s_mask[j] >> lane) & 1ull) w1 += p; else w0 += p;
        }
        s_W0[lane] = w0;
        s_W1[lane] = w1;
        W0[b * S + lane] = w0;
        W1[b * S + lane] = w1;
    }
    __syncthreads();

    // keys_out: row r reads columns c0,c1 with weights from W{t}
    {
        const int r   = lane;
        const int loc = r & 15;
        const int sec = r & ~15;
        const int t   = loc >> 3;      // 0 -> out0 rows, 1 -> out1 rows
        const int q   = loc & 7;
        const int c0  = sec + 2 * q;
        const int c1  = c0 + 1;
        const float wa = t ? s_W1[c0] : s_W0[c0];
        const float wb = t ? s_W1[c1] : s_W0[c1];
        keys_out[b * S + r] = wa * keys[b * S + c0] + wb * keys[b * S + c1];
    }
}

// ---------------------------------------------------------------------------
// Kernel 2: the streaming apply.
// Each block handles one (batch, column-pair): rows r0=sec+q and r1=sec+8+q
// both consume input rows c0=sec+2q, c1=c0+1 -> read the pair once, write
// both output rows. Input read exactly once overall; output written once.
// ---------------------------------------------------------------------------
__global__ __launch_bounds__(256) void split_apply_kernel(
    const float* __restrict__ input,   // [BB][S][EE]
    const float* __restrict__ W0,      // [BB][S]
    const float* __restrict__ W1,      // [BB][S]
    float* __restrict__ out)           // [BB][S][EE]
{
    const int blk = blockIdx.x;
    const int b   = blk >> 5;        // / 32 pairs
    const int pr  = blk & 31;
    const int sec = (pr >> 3) << 4;  // section base (0,16,32,48)
    const int q   = pr & 7;
    const int c0  = sec + 2 * q;
    const int c1  = c0 + 1;
    const int r0  = sec + q;
    const int r1  = sec + 8 + q;

    const float wa0 = W0[b * S + c0], wb0 = W0[b * S + c1];
    const float wa1 = W1[b * S + c0], wb1 = W1[b * S + c1];

    const float4* __restrict__ in0 = (const float4*)(input + ((size_t)b * S + c0) * EE);
    const float4* __restrict__ in1 = (const float4*)(input + ((size_t)b * S + c1) * EE);
    float4* __restrict__ o0 = (float4*)(out + ((size_t)b * S + r0) * EE);
    float4* __restrict__ o1 = (float4*)(out + ((size_t)b * S + r1) * EE);

    const int t = threadIdx.x;
    #pragma unroll
    for (int it = 0; it < EE / 4 / 256; ++it) {   // 4 iterations
        const int idx = t + it * 256;
        const float4 x0 = in0[idx];
        const float4 x1 = in1[idx];
        float4 y0, y1;
        y0.x = wa0 * x0.x + wb0 * x1.x;
        y0.y = wa0 * x0.y + wb0 * x1.y;
        y0.z = wa0 * x0.z + wb0 * x1.z;
        y0.w = wa0 * x0.w + wb0 * x1.w;
        y1.x = wa1 * x0.x + wb1 * x1.x;
        y1.y = wa1 * x0.y + wb1 * x1.y;
        y1.z = wa1 * x0.z + wb1 * x1.z;
        y1.w = wa1 * x0.w + wb1 * x1.w;
        o0[idx] = y0;
        o1[idx] = y1;
    }
}

extern "C" void kernel_launch(void* const* d_in, const int* in_sizes, int n_in,
                              void* d_out, int out_size, void* d_ws, size_t ws_size,
                              hipStream_t stream) {
    const float* input  = (const float*)d_in[0];   // [256,64,4096] f32
    const float* keys   = (const float*)d_in[1];   // [256,64] f32
    const float* offset = (const float*)d_in[2];   // [256,64] f32
    const int*   bits   = (const int*)  d_in[3];   // [256,16,64] i32

    float* out      = (float*)d_out;                      // [256,64,4096]
    float* keys_out = out + (size_t)BB * S * EE;          // [256,64]

    float* W0 = (float*)d_ws;          // [256*64]
    float* W1 = W0 + BB * S;           // [256*64]

    split_weights_kernel<<<BB, 64, 0, stream>>>(keys, offset, bits, W0, W1, keys_out);
    split_apply_kernel<<<BB * 32, 256, 0, stream>>>(input, W0, W1, out);
}

// Round 3
// 100.107 us; speedup vs baseline: 1.1244x; 1.1244x over previous
//
#include <hip/hip_runtime.h>

// Problem constants (from the reference)
#define BB     256   // batch
#define S      64    // SIZE
#define EE     4096  // E
#define NROWS  17    // 1 + ADDITIONAL

// native clang vector type (HIP's float4 is a class; the nontemporal
// builtins require a true vector/scalar type)
typedef float f32x4 __attribute__((ext_vector_type(4)));

// ---------------------------------------------------------------------------
// Fused kernel. Grid = BB*32 blocks (one per (batch, column-pair)), 256 thr.
//
// Math recap: the scatter matrix M has, per row r, at most 2 nonzeros at
// columns c0=sec+2q, c1=c0+1 (sec=r&~15, q=(r&15)&7, t=(r&15)>=8) with
// values W[t][c0], W[t][c1], where
//   W1[i] = sum_j probs'[j] * bit_ji ,  W0[i] = sum_j probs'[j] * (1-bit_ji)
// over the 17 choice rows (probs normalized over all 17, then later
// duplicates zeroed — reference order).
//
// Each block:
//   1. issues its 8 streaming float4 input loads (nontemporal) FIRST,
//   2. recomputes the per-batch weights redundantly under that latency
//      (ballot-packed uint64 masks, f32 products, dup-zeroing),
//   3. applies the 2x2 weights and streams out rows r0=sec+q, r1=sec+8+q.
// Input is read exactly once, output written exactly once.
// ---------------------------------------------------------------------------
__global__ __launch_bounds__(256) void split_fused_kernel(
    const float* __restrict__ input,    // [BB][S][EE]
    const float* __restrict__ keys,     // [BB][S]
    const float* __restrict__ offset,   // [BB][S]
    const int*   __restrict__ bits,     // [BB][16][S]
    float* __restrict__ out,            // [BB][S][EE]
    float* __restrict__ keys_out)       // [BB][S]
{
    const int blk  = blockIdx.x;
    const int b    = blk >> 5;
    const int pr   = blk & 31;
    const int tid  = threadIdx.x;
    const int lane = tid & 63;
    const int wv   = tid >> 6;

    const int sec = (pr >> 3) << 4;   // 0,16,32,48
    const int q   = pr & 7;
    const int c0  = sec + 2 * q;
    const int c1  = c0 + 1;
    const int r0  = sec + q;
    const int r1  = sec + 8 + q;

    // ---- 1. issue streaming input loads first (overlap weights preamble) ----
    const f32x4* __restrict__ in0 = (const f32x4*)(input + ((size_t)b * S + c0) * EE);
    const f32x4* __restrict__ in1 = (const f32x4*)(input + ((size_t)b * S + c1) * EE);
    f32x4 x0[4], x1[4];
    #pragma unroll
    for (int it = 0; it < 4; ++it) {
        x0[it] = __builtin_nontemporal_load(&in0[tid + it * 256]);
        x1[it] = __builtin_nontemporal_load(&in1[tid + it * 256]);
    }

    // ---- 2. per-batch weights (redundant per block; bits/offset L2-cached) --
    __shared__ float              s_off[S];
    __shared__ unsigned long long s_mask[NROWS];
    __shared__ float              s_prob[NROWS];
    __shared__ float              s_W0[S], s_W1[S];
    __shared__ float              s_sum;

    const float off = offset[b * S + lane];
    if (wv == 0) {
        s_off[lane] = off;
        // first choice row: round-half-even of offset (matches jnp.round)
        unsigned long long m0 = __ballot((int)rintf(off) == 1);
        if (lane == 0) s_mask[0] = m0;
    }
    // 16 sampled rows: wave w packs rows 4w..4w+3
    #pragma unroll
    for (int j = 0; j < 4; ++j) {
        const int row = wv * 4 + j;
        const int bit = bits[((size_t)b * 16 + row) * S + lane];
        unsigned long long m = __ballot(bit == 1);
        if (lane == 0) s_mask[1 + row] = m;
    }
    __syncthreads();

    if (tid < NROWS) {
        const unsigned long long mk = s_mask[tid];
        float p = 1.0f;
        #pragma unroll
        for (int i = 0; i < S; ++i) {
            const float o = s_off[i];
            p *= ((mk >> i) & 1ull) ? o : (1.0f - o);
        }
        s_prob[tid] = p;
    }
    __syncthreads();

    if (tid == 0) {
        float sum = 0.0f;
        #pragma unroll
        for (int j = 0; j < NROWS; ++j) sum += s_prob[j];
        s_sum = sum;
    }
    __syncthreads();

    // normalize over all 17 (dups included), THEN zero later duplicates
    if (tid < NROWS) {
        const unsigned long long mk = s_mask[tid];
        bool dup = false;
        for (int k = 0; k < tid; ++k) dup |= (s_mask[k] == mk);
        s_prob[tid] = dup ? 0.0f : (s_prob[tid] / s_sum);
    }
    __syncthreads();

    if (tid < S) {
        float w0 = 0.0f, w1 = 0.0f;
        #pragma unroll
        for (int j = 0; j < NROWS; ++j) {
            const float p = s_prob[j];
            if ((s_mask[j] >> tid) & 1ull) w1 += p; else w0 += p;
        }
        s_W0[tid] = w0;
        s_W1[tid] = w1;
    }
    __syncthreads();

    // keys_out: one block per batch writes it (rows have <=2 nnz)
    if (pr == 0 && tid < S) {
        const int loc = tid & 15;
        const int ksec = tid & ~15;
        const int kt  = loc >> 3;
        const int kq  = loc & 7;
        const int kc0 = ksec + 2 * kq;
        const int kc1 = kc0 + 1;
        const float wa = kt ? s_W1[kc0] : s_W0[kc0];
        const float wb = kt ? s_W1[kc1] : s_W0[kc1];
        keys_out[b * S + tid] = wa * keys[b * S + kc0] + wb * keys[b * S + kc1];
    }

    // ---- 3. apply 2x2 weights and stream out ----
    const float wa0 = s_W0[c0], wb0 = s_W0[c1];
    const float wa1 = s_W1[c0], wb1 = s_W1[c1];

    f32x4* __restrict__ o0 = (f32x4*)(out + ((size_t)b * S + r0) * EE);
    f32x4* __restrict__ o1 = (f32x4*)(out + ((size_t)b * S + r1) * EE);

    #pragma unroll
    for (int it = 0; it < 4; ++it) {
        const int idx = tid + it * 256;
        f32x4 y0, y1;
        y0.x = wa0 * x0[it].x + wb0 * x1[it].x;
        y0.y = wa0 * x0[it].y + wb0 * x1[it].y;
        y0.z = wa0 * x0[it].z + wb0 * x1[it].z;
        y0.w = wa0 * x0[it].w + wb0 * x1[it].w;
        y1.x = wa1 * x0[it].x + wb1 * x1[it].x;
        y1.y = wa1 * x0[it].y + wb1 * x1[it].y;
        y1.z = wa1 * x0[it].z + wb1 * x1[it].z;
        y1.w = wa1 * x0[it].w + wb1 * x1[it].w;
        __builtin_nontemporal_store(y0, &o0[idx]);
        __builtin_nontemporal_store(y1, &o1[idx]);
    }
}

extern "C" void kernel_launch(void* const* d_in, const int* in_sizes, int n_in,
                              void* d_out, int out_size, void* d_ws, size_t ws_size,
                              hipStream_t stream) {
    const float* input  = (const float*)d_in[0];   // [256,64,4096] f32
    const float* keys   = (const float*)d_in[1];   // [256,64] f32
    const float* offset = (const float*)d_in[2];   // [256,64] f32
    const int*   bits   = (const int*)  d_in[3];   // [256,16,64] i32

    float* out      = (float*)d_out;                  // [256,64,4096]
    float* keys_out = out + (size_t)BB * S * EE;      // [256,64]

    split_fused_kernel<<<BB * 32, 256, 0, stream>>>(input, keys, offset, bits,
                                                    out, keys_out);
}

// Round 4
// 96.149 us; speedup vs baseline: 1.1707x; 1.0412x over previous
//
#include <hip/hip_runtime.h>

// Problem constants (from the reference)
#define BB     256   // batch
#define S      64    // SIZE
#define EE     4096  // E
#define NROWS  17    // 1 + ADDITIONAL

// native clang vector type (HIP's float4 is a class; the nontemporal
// builtins require a true vector/scalar type)
typedef float f32x4 __attribute__((ext_vector_type(4)));

// ---------------------------------------------------------------------------
// Kernel 1: per-batch weight computation (tiny: 256 blocks x 64 threads).
//   - pack the 17 choice rows into uint64 masks via __ballot (lane i = col i)
//   - prob[j] = prod_i (bit ? off[i] : 1-off[i])   (f32, like the reference)
//   - normalize over ALL 17 rows, THEN zero later duplicates (reference order)
//   - W1[i] = sum_j probs'[j]*bit_ji ; W0[i] = sum_j probs'[j]*(1-bit_ji)
//   - keys_out[b,r] = wa*keys[c0] + wb*keys[c1]  (each M-row has <=2 nnz)
// ---------------------------------------------------------------------------
__global__ __launch_bounds__(64) void split_weights_kernel(
    const float* __restrict__ keys,     // [BB][S]
    const float* __restrict__ offset,   // [BB][S]
    const int*   __restrict__ bits,     // [BB][16][S]
    float* __restrict__ W0,             // [BB][S]
    float* __restrict__ W1,             // [BB][S]
    float* __restrict__ keys_out)       // [BB][S]
{
    const int b    = blockIdx.x;
    const int lane = threadIdx.x;   // 0..63, one full wave

    __shared__ float              s_off[S];
    __shared__ unsigned long long s_mask[NROWS];
    __shared__ float              s_prob[NROWS];
    __shared__ float              s_W0[S], s_W1[S];
    __shared__ float              s_sum;

    const float off = offset[b * S + lane];
    s_off[lane] = off;

    // first row: round-half-even of offset (matches jnp.round)
    unsigned long long m = __ballot((int)rintf(off) == 1);
    if (lane == 0) s_mask[0] = m;
    for (int j = 0; j < NROWS - 1; ++j) {
        const int bit = bits[((size_t)b * (NROWS - 1) + j) * S + lane];
        m = __ballot(bit == 1);
        if (lane == 0) s_mask[1 + j] = m;
    }
    __syncthreads();

    if (lane < NROWS) {
        const unsigned long long mk = s_mask[lane];
        float p = 1.0f;
        #pragma unroll
        for (int i = 0; i < S; ++i) {
            const float o = s_off[i];
            p *= ((mk >> i) & 1ull) ? o : (1.0f - o);
        }
        s_prob[lane] = p;
    }
    __syncthreads();

    if (lane == 0) {
        float sum = 0.0f;
        #pragma unroll
        for (int j = 0; j < NROWS; ++j) sum += s_prob[j];
        s_sum = sum;
    }
    __syncthreads();

    // normalize over all 17 (dups included), THEN zero later duplicates
    if (lane < NROWS) {
        const unsigned long long mk = s_mask[lane];
        bool dup = false;
        for (int k = 0; k < lane; ++k) dup |= (s_mask[k] == mk);
        s_prob[lane] = dup ? 0.0f : (s_prob[lane] / s_sum);
    }
    __syncthreads();

    {
        float w0 = 0.0f, w1 = 0.0f;
        #pragma unroll
        for (int j = 0; j < NROWS; ++j) {
            const float p = s_prob[j];
            if ((s_mask[j] >> lane) & 1ull) w1 += p; else w0 += p;
        }
        s_W0[lane] = w0;
        s_W1[lane] = w1;
        W0[b * S + lane] = w0;
        W1[b * S + lane] = w1;
    }
    __syncthreads();

    {
        const int loc = lane & 15;
        const int sec = lane & ~15;
        const int t   = loc >> 3;
        const int q   = loc & 7;
        const int c0  = sec + 2 * q;
        const int c1  = c0 + 1;
        const float wa = t ? s_W1[c0] : s_W0[c0];
        const float wb = t ? s_W1[c1] : s_W0[c1];
        keys_out[b * S + lane] = wa * keys[b * S + c0] + wb * keys[b * S + c1];
    }
}

// ---------------------------------------------------------------------------
// Kernel 2: pure-stream apply. No LDS, no barriers, no ballots.
// One block per (batch, column-pair): rows r0=sec+q, r1=sec+8+q both consume
// input rows c0=sec+2q, c1=c0+1. Input read exactly once, output written once.
// The 4 weight scalars are block-uniform -> scalar loads, resolved while the
// first nontemporal dwordx4 loads are in flight.
// ---------------------------------------------------------------------------
__global__ __launch_bounds__(256) void split_apply_kernel(
    const float* __restrict__ input,   // [BB][S][EE]
    const float* __restrict__ W0,      // [BB][S]
    const float* __restrict__ W1,      // [BB][S]
    float* __restrict__ out)           // [BB][S][EE]
{
    const int blk = blockIdx.x;
    const int b   = blk >> 5;
    const int pr  = blk & 31;
    const int sec = (pr >> 3) << 4;  // 0,16,32,48
    const int q   = pr & 7;
    const int c0  = sec + 2 * q;
    const int c1  = c0 + 1;
    const int r0  = sec + q;
    const int r1  = sec + 8 + q;

    const float wa0 = W0[b * S + c0], wb0 = W0[b * S + c1];
    const float wa1 = W1[b * S + c0], wb1 = W1[b * S + c1];

    const f32x4* __restrict__ in0 = (const f32x4*)(input + ((size_t)b * S + c0) * EE);
    const f32x4* __restrict__ in1 = (const f32x4*)(input + ((size_t)b * S + c1) * EE);
    f32x4* __restrict__ o0 = (f32x4*)(out + ((size_t)b * S + r0) * EE);
    f32x4* __restrict__ o1 = (f32x4*)(out + ((size_t)b * S + r1) * EE);

    const int tid = threadIdx.x;

    // issue all 8 input loads up front; compiler staggers vmcnt waits
    f32x4 x0[4], x1[4];
    #pragma unroll
    for (int it = 0; it < 4; ++it) {
        x0[it] = __builtin_nontemporal_load(&in0[tid + it * 256]);
        x1[it] = __builtin_nontemporal_load(&in1[tid + it * 256]);
    }

    #pragma unroll
    for (int it = 0; it < 4; ++it) {
        const int idx = tid + it * 256;
        f32x4 y0, y1;
        y0.x = wa0 * x0[it].x + wb0 * x1[it].x;
        y0.y = wa0 * x0[it].y + wb0 * x1[it].y;
        y0.z = wa0 * x0[it].z + wb0 * x1[it].z;
        y0.w = wa0 * x0[it].w + wb0 * x1[it].w;
        y1.x = wa1 * x0[it].x + wb1 * x1[it].x;
        y1.y = wa1 * x0[it].y + wb1 * x1[it].y;
        y1.z = wa1 * x0[it].z + wb1 * x1[it].z;
        y1.w = wa1 * x0[it].w + wb1 * x1[it].w;
        __builtin_nontemporal_store(y0, &o0[idx]);
        __builtin_nontemporal_store(y1, &o1[idx]);
    }
}

extern "C" void kernel_launch(void* const* d_in, const int* in_sizes, int n_in,
                              void* d_out, int out_size, void* d_ws, size_t ws_size,
                              hipStream_t stream) {
    const float* input  = (const float*)d_in[0];   // [256,64,4096] f32
    const float* keys   = (const float*)d_in[1];   // [256,64] f32
    const float* offset = (const float*)d_in[2];   // [256,64] f32
    const int*   bits   = (const int*)  d_in[3];   // [256,16,64] i32

    float* out      = (float*)d_out;                  // [256,64,4096]
    float* keys_out = out + (size_t)BB * S * EE;      // [256,64]

    float* W0 = (float*)d_ws;          // [256*64]
    float* W1 = W0 + BB * S;           // [256*64]

    split_weights_kernel<<<BB, 64, 0, stream>>>(keys, offset, bits, W0, W1, keys_out);
    split_apply_kernel<<<BB * 32, 256, 0, stream>>>(input, W0, W1, out);
}

// Round 5
// 95.285 us; speedup vs baseline: 1.1814x; 1.0091x over previous
//
#include <hip/hip_runtime.h>

// Problem constants (from the reference)
#define BB     256   // batch
#define S      64    // SIZE
#define EE     4096  // E
#define NROWS  17    // 1 + ADDITIONAL

// native clang vector type (HIP's float4 is a class; the nontemporal
// builtins require a true vector/scalar type)
typedef float f32x4 __attribute__((ext_vector_type(4)));

// ---------------------------------------------------------------------------
// Kernel 1: per-batch weights. One wave (64 threads) per batch.
// Latency-minimal: ALL global loads issued up front (one round-trip),
// no LDS, no barriers; products via shfl_xor butterfly (all lanes busy).
//
//   prob[j]  = prod_i (bit_ji ? off_i : 1-off_i), normalized over all 17,
//              then later-duplicate rows zeroed (reference order).
//   W1[i]    = sum_j prob'[j]*bit_ji ; W0[i] = sum_j prob'[j]*(1-bit_ji)
//   keys_out[b,r] = wa*keys[c0] + wb*keys[c1]  (each M-row has <=2 nnz)
// ---------------------------------------------------------------------------
__global__ __launch_bounds__(64) void split_weights_kernel(
    const float* __restrict__ keys,     // [BB][S]
    const float* __restrict__ offset,   // [BB][S]
    const int*   __restrict__ bits,     // [BB][16][S]
    float* __restrict__ W0,             // [BB][S]
    float* __restrict__ W1,             // [BB][S]
    float* __restrict__ keys_out)       // [BB][S]
{
    const int b    = blockIdx.x;
    const int lane = threadIdx.x;   // 0..63 == column index

    // ---- issue every global load now (independent, all in flight) ----
    const float off = offset[b * S + lane];
    int bitv[16];
    #pragma unroll
    for (int j = 0; j < 16; ++j)
        bitv[j] = bits[((size_t)b * 16 + j) * S + lane];

    const int loc = lane & 15;
    const int sec = lane & ~15;
    const int t   = loc >> 3;
    const int q   = loc & 7;
    const int c0  = sec + 2 * q;
    const int c1  = c0 + 1;
    const float k0 = keys[b * S + c0];
    const float k1 = keys[b * S + c1];

    // ---- 17 choice-row masks, replicated into every lane ----
    unsigned long long mask[NROWS];
    mask[0] = __ballot((int)rintf(off) == 1);   // jnp.round = half-even
    #pragma unroll
    for (int j = 0; j < 16; ++j)
        mask[1 + j] = __ballot(bitv[j] == 1);

    // ---- probability products: lane's factor, then 64-lane butterfly ----
    const float one_m_off = 1.0f - off;
    float prob[NROWS];
    #pragma unroll
    for (int j = 0; j < NROWS; ++j) {
        float v = ((mask[j] >> lane) & 1ull) ? off : one_m_off;
        #pragma unroll
        for (int d = 1; d < 64; d <<= 1)
            v *= __shfl_xor(v, d, 64);
        prob[j] = v;            // all lanes hold the full product
    }

    // ---- normalize over ALL 17, then zero later duplicates ----
    float sum = 0.0f;
    #pragma unroll
    for (int j = 0; j < NROWS; ++j) sum += prob[j];
    const float inv = 1.0f / sum;
    #pragma unroll
    for (int j = 0; j < NROWS; ++j) {
        bool dup = false;
        #pragma unroll
        for (int k = 0; k < NROWS; ++k)
            if (k < j) dup |= (mask[k] == mask[j]);
        prob[j] = dup ? 0.0f : prob[j] * inv;
    }

    // ---- per-column split weights (lane = column) ----
    float w0 = 0.0f, w1 = 0.0f;
    #pragma unroll
    for (int j = 0; j < NROWS; ++j) {
        if ((mask[j] >> lane) & 1ull) w1 += prob[j]; else w0 += prob[j];
    }
    W0[b * S + lane] = w0;
    W1[b * S + lane] = w1;

    // ---- keys_out via shuffles (need W at columns c0, c1) ----
    const float wa0 = __shfl(w0, c0, 64), wa1 = __shfl(w1, c0, 64);
    const float wb0 = __shfl(w0, c1, 64), wb1 = __shfl(w1, c1, 64);
    const float wa = t ? wa1 : wa0;
    const float wb = t ? wb1 : wb0;
    keys_out[b * S + lane] = wa * k0 + wb * k1;
}

// ---------------------------------------------------------------------------
// Kernel 2: pure-stream apply. No LDS, no barriers, no ballots.
// One block per (batch, column-pair): rows r0=sec+q, r1=sec+8+q both consume
// input rows c0=sec+2q, c1=c0+1. Input read exactly once, output written once.
// ---------------------------------------------------------------------------
__global__ __launch_bounds__(256) void split_apply_kernel(
    const float* __restrict__ input,   // [BB][S][EE]
    const float* __restrict__ W0,      // [BB][S]
    const float* __restrict__ W1,      // [BB][S]
    float* __restrict__ out)           // [BB][S][EE]
{
    const int blk = blockIdx.x;
    const int b   = blk >> 5;
    const int pr  = blk & 31;
    const int sec = (pr >> 3) << 4;  // 0,16,32,48
    const int q   = pr & 7;
    const int c0  = sec + 2 * q;
    const int c1  = c0 + 1;
    const int r0  = sec + q;
    const int r1  = sec + 8 + q;

    const float wa0 = W0[b * S + c0], wb0 = W0[b * S + c1];
    const float wa1 = W1[b * S + c0], wb1 = W1[b * S + c1];

    const f32x4* __restrict__ in0 = (const f32x4*)(input + ((size_t)b * S + c0) * EE);
    const f32x4* __restrict__ in1 = (const f32x4*)(input + ((size_t)b * S + c1) * EE);
    f32x4* __restrict__ o0 = (f32x4*)(out + ((size_t)b * S + r0) * EE);
    f32x4* __restrict__ o1 = (f32x4*)(out + ((size_t)b * S + r1) * EE);

    const int tid = threadIdx.x;

    // issue all 8 input loads up front; compiler staggers vmcnt waits
    f32x4 x0[4], x1[4];
    #pragma unroll
    for (int it = 0; it < 4; ++it) {
        x0[it] = __builtin_nontemporal_load(&in0[tid + it * 256]);
        x1[it] = __builtin_nontemporal_load(&in1[tid + it * 256]);
    }

    #pragma unroll
    for (int it = 0; it < 4; ++it) {
        const int idx = tid + it * 256;
        f32x4 y0, y1;
        y0.x = wa0 * x0[it].x + wb0 * x1[it].x;
        y0.y = wa0 * x0[it].y + wb0 * x1[it].y;
        y0.z = wa0 * x0[it].z + wb0 * x1[it].z;
        y0.w = wa0 * x0[it].w + wb0 * x1[it].w;
        y1.x = wa1 * x0[it].x + wb1 * x1[it].x;
        y1.y = wa1 * x0[it].y + wb1 * x1[it].y;
        y1.z = wa1 * x0[it].z + wb1 * x1[it].z;
        y1.w = wa1 * x0[it].w + wb1 * x1[it].w;
        __builtin_nontemporal_store(y0, &o0[idx]);
        __builtin_nontemporal_store(y1, &o1[idx]);
    }
}

extern "C" void kernel_launch(void* const* d_in, const int* in_sizes, int n_in,
                              void* d_out, int out_size, void* d_ws, size_t ws_size,
                              hipStream_t stream) {
    const float* input  = (const float*)d_in[0];   // [256,64,4096] f32
    const float* keys   = (const float*)d_in[1];   // [256,64] f32
    const float* offset = (const float*)d_in[2];   // [256,64] f32
    const int*   bits   = (const int*)  d_in[3];   // [256,16,64] i32

    float* out      = (float*)d_out;                  // [256,64,4096]
    float* keys_out = out + (size_t)BB * S * EE;      // [256,64]

    float* W0 = (float*)d_ws;          // [256*64]
    float* W1 = W0 + BB * S;           // [256*64]

    split_weights_kernel<<<BB, 64, 0, stream>>>(keys, offset, bits, W0, W1, keys_out);
    split_apply_kernel<<<BB * 32, 256, 0, stream>>>(input, W0, W1, out);
}